// Round 2
// baseline (125.070 us; speedup 1.0000x reference)
//
#include <hip/hip_runtime.h>

typedef __attribute__((ext_vector_type(8))) short short8;
typedef __attribute__((ext_vector_type(8))) unsigned short u16x8;
typedef __attribute__((ext_vector_type(4))) float f32x4;

#define L2E 1.44269504f

__device__ __forceinline__ unsigned short f2bf(float f){
  unsigned u = __float_as_uint(f);
  u += 0x7fffu + ((u >> 16) & 1u);
  return (unsigned short)(u >> 16);
}
__device__ __forceinline__ float bf2f(unsigned short h){
  return __uint_as_float(((unsigned)h) << 16);
}

// ---------------- prep: fold score_w through q_w / kv_w ----------------
__global__ void prep_vecs(const float* __restrict__ qw, const float* __restrict__ qb,
                          const float* __restrict__ kvw, const float* __restrict__ kvb,
                          const float* __restrict__ scw, const float* __restrict__ scb,
                          float* __restrict__ qv, float* __restrict__ kvv,
                          float* __restrict__ cqck){
  int d = threadIdx.x; // 0..127
  const float4* qr = (const float4*)(qw + d*128);
  const float4* kr = (const float4*)(kvw + d*256);
  float a = 0.f, c = 0.f;
  #pragma unroll 8
  for (int i = 0; i < 32; ++i){
    float4 q4 = qr[i];
    float4 w4 = *(const float4*)(scw + i*4);
    a = fmaf(q4.x, w4.x, a); a = fmaf(q4.y, w4.y, a);
    a = fmaf(q4.z, w4.z, a); a = fmaf(q4.w, w4.w, a);
    float4 k4 = kr[i];
    float4 v4 = *(const float4*)(scw + 128 + i*4);
    c = fmaf(k4.x, v4.x, c); c = fmaf(k4.y, v4.y, c);
    c = fmaf(k4.z, v4.z, c); c = fmaf(k4.w, v4.w, c);
  }
  qv[d] = a; kvv[d] = c;
  if (d == 0){
    float cq = scb[0], ck = 0.f;
    #pragma unroll 8
    for (int i = 0; i < 32; ++i){
      float4 qb4 = *(const float4*)(qb + i*4);
      float4 w4  = *(const float4*)(scw + i*4);
      float4 kb4 = *(const float4*)(kvb + i*4);
      float4 v4  = *(const float4*)(scw + 128 + i*4);
      cq = fmaf(qb4.x, w4.x, cq); cq = fmaf(qb4.y, w4.y, cq);
      cq = fmaf(qb4.z, w4.z, cq); cq = fmaf(qb4.w, w4.w, cq);
      ck = fmaf(kb4.x, v4.x, ck); ck = fmaf(kb4.y, v4.y, ck);
      ck = fmaf(kb4.z, v4.z, ck); ck = fmaf(kb4.w, v4.w, ck);
    }
    cqck[0] = cq; cqck[1] = ck;
  }
}

// W2T[ho][din] = sum_h kv_w[din][128+h] * out_w[h][ho]   (bf16, transposed)
// c2[ho] = sum_h kv_b[128+h] * out_w[h][ho] + out_b[ho]
__global__ __launch_bounds__(256) void prep_w2(const float* __restrict__ kvw,
                          const float* __restrict__ kvb,
                          const float* __restrict__ outw, const float* __restrict__ outb,
                          unsigned short* __restrict__ w2t, float* __restrict__ c2){
  int blk = blockIdx.x;
  if (blk < 64){
    int idx = blk*256 + threadIdx.x;
    int di = idx >> 7, ho = idx & 127;     // kvw read wave-uniform, outw coalesced
    const float* kr = kvw + di*256 + 128;
    float s = 0.f;
    for (int h = 0; h < 128; ++h) s = fmaf(kr[h], outw[h*128 + ho], s);
    w2t[ho*128 + di] = f2bf(s);
  } else if (threadIdx.x < 128){
    int ho = threadIdx.x;
    float s = outb[ho];
    for (int h = 0; h < 128; ++h) s = fmaf(kvb[128 + h], outw[h*128 + ho], s);
    c2[ho] = s;
  }
}

// sq'[b*1024+m] = L2E * (mf[b,m,:].qv + cq)
__global__ __launch_bounds__(256) void prep_sq(const float* __restrict__ mf,
                          const float* __restrict__ qv, const float* __restrict__ cqck,
                          float* __restrict__ sqp){
  int row = blockIdx.x*4 + (threadIdx.x >> 6);
  int lane = threadIdx.x & 63;
  float s = mf[row*128 + lane] * qv[lane] + mf[row*128 + 64 + lane] * qv[64 + lane];
  #pragma unroll
  for (int o = 32; o; o >>= 1) s += __shfl_xor(s, o, 64);
  if (lane == 0) sqp[row] = L2E * (s + cqck[0]);
}

// sk'[b*4096+c] = L2E * (of[b,c,:].kvv + ck) ; ofT[b][d][c] = bf16(of[b][c][d])
__global__ __launch_bounds__(256) void prep_sk_tr(const float* __restrict__ of,
                          const float* __restrict__ kvv, const float* __restrict__ cqck,
                          float* __restrict__ skp, unsigned short* __restrict__ ofT){
  __shared__ unsigned short tile[64*130];
  int b  = blockIdx.x >> 6;
  int c0 = (blockIdx.x & 63) << 6;
  int t  = threadIdx.x;
  int r  = t >> 2, dq = (t & 3) << 5;
  const float* src = of + ((size_t)(b*4096 + c0 + r))*128 + dq;
  float part = 0.f;
  #pragma unroll
  for (int j = 0; j < 32; j += 4){
    float4 v = *(const float4*)(src + j);
    part = fmaf(v.x, kvv[dq + j],     part);
    part = fmaf(v.y, kvv[dq + j + 1], part);
    part = fmaf(v.z, kvv[dq + j + 2], part);
    part = fmaf(v.w, kvv[dq + j + 3], part);
    tile[r*130 + dq + j]     = f2bf(v.x);
    tile[r*130 + dq + j + 1] = f2bf(v.y);
    tile[r*130 + dq + j + 2] = f2bf(v.z);
    tile[r*130 + dq + j + 3] = f2bf(v.w);
  }
  part += __shfl_xor(part, 1, 64);
  part += __shfl_xor(part, 2, 64);
  if ((t & 3) == 0) skp[b*4096 + c0 + r] = L2E * (part + cqck[1]);
  __syncthreads();
  int d = t >> 1, chh = (t & 1) << 5;
  unsigned short* dst = ofT + ((size_t)(b*128 + d))*4096 + c0 + chh;
  #pragma unroll
  for (int j = 0; j < 32; j += 8){
    u16x8 v;
    #pragma unroll
    for (int k = 0; k < 8; ++k) v[k] = tile[(chh + j + k)*130 + d];
    *(u16x8*)(dst + j) = v;
  }
}

// ---------------- main fused kernel (C-split) ----------------
// grid = 512 << csl2. blk -> (b, cs, mt): mt = blk&63, bc = blk>>6, cs = bc&(CS-1), b = bc>>csl2.
// Each block: 16 m-rows, C range [cs*4096/CS, ...) as (16>>csl2) chunks of 256.
// Writes partial acc (16x128 f32) and partial rowsums to ws; no GEMM2 here.
__global__ __launch_bounds__(256, 8) void attn_main(
    const float* __restrict__ mask, const float* __restrict__ sqp,
    const float* __restrict__ skp, const unsigned short* __restrict__ ofT,
    float* __restrict__ pacc, float* __restrict__ prs, int csl2)
{
  __shared__ unsigned short Pl[2][16*256];   // 16 KB
  const int blk = blockIdx.x;
  const int mt = blk & 63;
  const int bc = blk >> 6;
  const int cs = bc & ((1 << csl2) - 1);
  const int b  = bc >> csl2;
  const int m0 = mt << 4;
  const int c0 = cs << (12 - csl2);
  const int nch = 16 >> csl2;
  const int t  = threadIdx.x;
  const int w  = t >> 6;
  const int l  = t & 63;
  const int l15 = l & 15, l4 = l >> 4;

  const int r = t >> 4;
  const int csub = (t & 15) << 4;
  const int xr = (r & 7) << 4;
  const float* mrow  = mask + ((size_t)(b*1024 + m0 + r))*4096 + c0 + csub;
  const float* skrow = skp + b*4096 + c0 + csub;
  const float sqv = sqp[b*1024 + m0 + r];

  const unsigned short* bp0 = ofT + ((size_t)(b*128 + w*32 + l15))*4096 + c0 + l4*8;
  const unsigned short* bp1 = bp0 + 16*4096;

  f32x4 acc0 = {0.f,0.f,0.f,0.f}, acc1 = {0.f,0.f,0.f,0.f};
  float rsum = 0.f;

  for (int ch = 0; ch < nch; ++ch){
    const int cb = ch << 8;
    float4 mv[4], sv[4];
    #pragma unroll
    for (int i = 0; i < 4; ++i){
      mv[i] = *(const float4*)(mrow + cb + i*4);
      sv[i] = *(const float4*)(skrow + cb + i*4);
    }
    float pvals[16];
    #pragma unroll
    for (int i = 0; i < 4; ++i){
      float sx[4] = {sv[i].x, sv[i].y, sv[i].z, sv[i].w};
      float mx[4] = {mv[i].x, mv[i].y, mv[i].z, mv[i].w};
      #pragma unroll
      for (int j = 0; j < 4; ++j){
        float s = sqv + sx[j];            // log2-domain
        s = fmaxf(s, 0.01f*s);            // leaky (positively homogeneous)
        s *= mx[j];                       // mask: 0 -> exp2(0)=1
        pvals[i*4 + j] = __builtin_amdgcn_exp2f(s);
      }
    }
    u16x8 plo, phi;
    #pragma unroll
    for (int j = 0; j < 8; ++j){
      unsigned short h0 = f2bf(pvals[j]), h1 = f2bf(pvals[8 + j]);
      plo[j] = h0; phi[j] = h1;
      rsum += bf2f(h0) + bf2f(h1);        // denominator matches bf16 numerator
    }
    char* base = (char*)&Pl[ch & 1][0] + r*512;
    *(u16x8*)(base + ((csub*2)      ^ xr)) = plo;
    *(u16x8*)(base + ((csub*2 + 16) ^ xr)) = phi;
    __syncthreads();
    const char* abase = (const char*)&Pl[ch & 1][0] + l15*512;
    const int xa = (l15 & 7) << 4;
    #pragma unroll
    for (int ks = 0; ks < 8; ++ks){
      short8 afrag = *(const short8*)(abase + ((ks*64 + l4*16) ^ xa));
      short8 bfr0  = *(const short8*)(bp0 + cb + ks*32);
      short8 bfr1  = *(const short8*)(bp1 + cb + ks*32);
      acc0 = __builtin_amdgcn_mfma_f32_16x16x32_bf16(afrag, bfr0, acc0, 0, 0, 0);
      acc1 = __builtin_amdgcn_mfma_f32_16x16x32_bf16(afrag, bfr1, acc1, 0, 0, 0);
    }
  }
  // partial rowsum: 16 lanes share row r
  rsum += __shfl_xor(rsum, 1, 64);
  rsum += __shfl_xor(rsum, 2, 64);
  rsum += __shfl_xor(rsum, 4, 64);
  rsum += __shfl_xor(rsum, 8, 64);
  if ((t & 15) == 0) prs[blk*16 + r] = rsum;
  // partial acc -> ws (f32, linear 16x128)
  float* pa = pacc + (size_t)blk * 2048;
  #pragma unroll
  for (int n = 0; n < 2; ++n){
    const f32x4 a = n ? acc1 : acc0;
    const int col = w*32 + n*16 + l15;
    #pragma unroll
    for (int j = 0; j < 4; ++j) pa[(l4*4 + j)*128 + col] = a[j];
  }
}

// ---------------- reduce partials + GEMM2 + normalize ----------------
__global__ __launch_bounds__(256) void reduce_gemm2(
    const float* __restrict__ pacc, const float* __restrict__ prs,
    const unsigned short* __restrict__ w2t, const float* __restrict__ c2,
    float* __restrict__ out, int csl2)
{
  __shared__ unsigned short A2[16*128];
  __shared__ float rs[16];
  const int bm = blockIdx.x;           // b*64 + mt
  const int b = bm >> 6, mt = bm & 63;
  const int CS = 1 << csl2;
  const int t = threadIdx.x;
  const int row = t >> 4, c8 = (t & 15) << 3;

  float a[8] = {0,0,0,0,0,0,0,0};
  for (int cs = 0; cs < CS; ++cs){
    const float* pb = pacc + ((size_t)(((b << csl2) + cs)*64 + mt))*2048 + row*128 + c8;
    f32x4 v0 = *(const f32x4*)pb;
    f32x4 v1 = *(const f32x4*)(pb + 4);
    a[0]+=v0[0]; a[1]+=v0[1]; a[2]+=v0[2]; a[3]+=v0[3];
    a[4]+=v1[0]; a[5]+=v1[1]; a[6]+=v1[2]; a[7]+=v1[3];
  }
  if (t < 16){
    float s = 0.f;
    for (int cs = 0; cs < CS; ++cs) s += prs[(((b << csl2) + cs)*64 + mt)*16 + t];
    rs[t] = s;
  }
  __syncthreads();
  const float rinv = 1.f / rs[row];
  u16x8 v;
  #pragma unroll
  for (int j = 0; j < 8; ++j) v[j] = f2bf(a[j] * rinv);
  *(u16x8*)((char*)A2 + row*256 + (((t & 15) << 4) ^ ((row & 7) << 4))) = v;
  __syncthreads();

  const int w = t >> 6, l = t & 63, l15 = l & 15, l4 = l >> 4;
  f32x4 o0 = {0.f,0.f,0.f,0.f}, o1 = {0.f,0.f,0.f,0.f};
  const unsigned short* wp0 = w2t + (size_t)(w*32 + l15)*128 + l4*8;
  const unsigned short* wp1 = wp0 + 16*128;
  const char* a2b = (const char*)A2 + l15*256;
  const int xa2 = (l15 & 7) << 4;
  #pragma unroll
  for (int ks = 0; ks < 4; ++ks){
    short8 afrag = *(const short8*)(a2b + ((ks*64 + l4*16) ^ xa2));
    short8 b0 = *(const short8*)(wp0 + ks*32);
    short8 b1 = *(const short8*)(wp1 + ks*32);
    o0 = __builtin_amdgcn_mfma_f32_16x16x32_bf16(afrag, b0, o0, 0, 0, 0);
    o1 = __builtin_amdgcn_mfma_f32_16x16x32_bf16(afrag, b1, o1, 0, 0, 0);
  }
  #pragma unroll
  for (int n = 0; n < 2; ++n){
    const f32x4 o = n ? o1 : o0;
    const int col = w*32 + n*16 + l15;
    const float cc = c2[col];
    #pragma unroll
    for (int j = 0; j < 4; ++j){
      const int orow = l4*4 + j;
      out[((size_t)(b*1024 + mt*16 + orow))*128 + col] = o[j] + cc;
    }
  }
}

extern "C" void kernel_launch(void* const* d_in, const int* in_sizes, int n_in,
                              void* d_out, int out_size, void* d_ws, size_t ws_size,
                              hipStream_t stream){
  const float* of   = (const float*)d_in[0];
  const float* mf   = (const float*)d_in[1];
  const float* mask = (const float*)d_in[2];
  const float* qw   = (const float*)d_in[3];
  const float* qb   = (const float*)d_in[4];
  const float* kvw  = (const float*)d_in[5];
  const float* kvb  = (const float*)d_in[6];
  const float* scw  = (const float*)d_in[7];
  const float* scb  = (const float*)d_in[8];
  const float* outw = (const float*)d_in[9];
  const float* outb = (const float*)d_in[10];
  float* out = (float*)d_out;

  char* ws = (char*)d_ws;
  unsigned short* ofT  = (unsigned short*)(ws);             // 8 MiB
  unsigned short* w2t  = (unsigned short*)(ws + 8388608);   // 32 KiB
  float* c2   = (float*)(ws + 8421376);
  float* sqp  = (float*)(ws + 8421888);
  float* skp  = (float*)(ws + 8454656);
  float* qv   = (float*)(ws + 8585728);
  float* kvv  = (float*)(ws + 8586240);
  float* cqck = (float*)(ws + 8586752);
  const size_t fixed_end = 8587008;

  // pick largest C-split that fits the workspace
  int csl2 = 2;
  for (; csl2 > 0; --csl2){
    size_t nblk = (size_t)512 << csl2;
    size_t need = fixed_end + nblk*16*4 + nblk*2048*4;
    if (need <= ws_size) break;
  }
  size_t nblk = (size_t)512 << csl2;
  float* prs  = (float*)(ws + fixed_end);
  float* pacc = (float*)(ws + fixed_end + nblk*16*4);

  prep_vecs<<<1, 128, 0, stream>>>(qw, qb, kvw, kvb, scw, scb, qv, kvv, cqck);
  prep_w2<<<65, 256, 0, stream>>>(kvw, kvb, outw, outb, w2t, c2);
  prep_sq<<<2048, 256, 0, stream>>>(mf, qv, cqck, sqp);
  prep_sk_tr<<<512, 256, 0, stream>>>(of, kvv, cqck, skp, ofT);
  attn_main<<<(int)nblk, 256, 0, stream>>>(mask, sqp, skp, ofT, pacc, prs, csl2);
  reduce_gemm2<<<512, 256, 0, stream>>>(pacc, prs, w2t, c2, out, csl2);
}

// Round 3
// 94.873 us; speedup vs baseline: 1.3183x; 1.3183x over previous
//
#include <hip/hip_runtime.h>

typedef __attribute__((ext_vector_type(8))) short short8;
typedef __attribute__((ext_vector_type(8))) unsigned short u16x8;
typedef __attribute__((ext_vector_type(4))) unsigned short u16x4;
typedef __attribute__((ext_vector_type(4))) float f32x4;

#define L2E 1.44269504f

__device__ __forceinline__ unsigned short f2bf(float f){
  unsigned u = __float_as_uint(f);
  u += 0x7fffu + ((u >> 16) & 1u);
  return (unsigned short)(u >> 16);
}
__device__ __forceinline__ float bf2f(unsigned short h){
  return __uint_as_float(((unsigned)h) << 16);
}

// ---------------- prep: fold score_w through q_w / kv_w ----------------
__global__ void prep_vecs(const float* __restrict__ qw, const float* __restrict__ qb,
                          const float* __restrict__ kvw, const float* __restrict__ kvb,
                          const float* __restrict__ scw, const float* __restrict__ scb,
                          float* __restrict__ qv, float* __restrict__ kvv,
                          float* __restrict__ cqck){
  int d = threadIdx.x; // 0..127
  const float4* qr = (const float4*)(qw + d*128);
  const float4* kr = (const float4*)(kvw + d*256);
  float a = 0.f, c = 0.f;
  #pragma unroll 8
  for (int i = 0; i < 32; ++i){
    float4 q4 = qr[i];
    float4 w4 = *(const float4*)(scw + i*4);
    a = fmaf(q4.x, w4.x, a); a = fmaf(q4.y, w4.y, a);
    a = fmaf(q4.z, w4.z, a); a = fmaf(q4.w, w4.w, a);
    float4 k4 = kr[i];
    float4 v4 = *(const float4*)(scw + 128 + i*4);
    c = fmaf(k4.x, v4.x, c); c = fmaf(k4.y, v4.y, c);
    c = fmaf(k4.z, v4.z, c); c = fmaf(k4.w, v4.w, c);
  }
  qv[d] = a; kvv[d] = c;
  if (d == 0){
    float cq = scb[0], ck = 0.f;
    #pragma unroll 8
    for (int i = 0; i < 32; ++i){
      float4 qb4 = *(const float4*)(qb + i*4);
      float4 w4  = *(const float4*)(scw + i*4);
      float4 kb4 = *(const float4*)(kvb + i*4);
      float4 v4  = *(const float4*)(scw + 128 + i*4);
      cq = fmaf(qb4.x, w4.x, cq); cq = fmaf(qb4.y, w4.y, cq);
      cq = fmaf(qb4.z, w4.z, cq); cq = fmaf(qb4.w, w4.w, cq);
      ck = fmaf(kb4.x, v4.x, ck); ck = fmaf(kb4.y, v4.y, ck);
      ck = fmaf(kb4.z, v4.z, ck); ck = fmaf(kb4.w, v4.w, ck);
    }
    cqck[0] = cq; cqck[1] = ck;
  }
}

// W2T[ho][din] = sum_h kv_w[din][128+h] * out_w[h][ho]   (bf16, transposed)
__global__ __launch_bounds__(256) void prep_w2(const float* __restrict__ kvw,
                          const float* __restrict__ kvb,
                          const float* __restrict__ outw, const float* __restrict__ outb,
                          unsigned short* __restrict__ w2t, float* __restrict__ c2){
  int blk = blockIdx.x;
  if (blk < 64){
    int idx = blk*256 + threadIdx.x;
    int di = idx >> 7, ho = idx & 127;
    const float* kr = kvw + di*256 + 128;
    float s = 0.f;
    for (int h = 0; h < 128; ++h) s = fmaf(kr[h], outw[h*128 + ho], s);
    w2t[ho*128 + di] = f2bf(s);
  } else if (threadIdx.x < 128){
    int ho = threadIdx.x;
    float s = outb[ho];
    for (int h = 0; h < 128; ++h) s = fmaf(kvb[128 + h], outw[h*128 + ho], s);
    c2[ho] = s;
  }
}

// sq'[b*1024+m] = L2E * (mf[b,m,:].qv + cq)
__global__ __launch_bounds__(256) void prep_sq(const float* __restrict__ mf,
                          const float* __restrict__ qv, const float* __restrict__ cqck,
                          float* __restrict__ sqp){
  int row = blockIdx.x*4 + (threadIdx.x >> 6);
  int lane = threadIdx.x & 63;
  float s = mf[row*128 + lane] * qv[lane] + mf[row*128 + 64 + lane] * qv[64 + lane];
  #pragma unroll
  for (int o = 32; o; o >>= 1) s += __shfl_xor(s, o, 64);
  if (lane == 0) sqp[row] = L2E * (s + cqck[0]);
}

// sk'[b*4096+c] = L2E * (of[b,c,:].kvv + ck) ; ofT[b][d][c] = bf16(of[b][c][d])
__global__ __launch_bounds__(256) void prep_sk_tr(const float* __restrict__ of,
                          const float* __restrict__ kvv, const float* __restrict__ cqck,
                          float* __restrict__ skp, unsigned short* __restrict__ ofT){
  __shared__ unsigned short tile[64*130];
  int b  = blockIdx.x >> 6;
  int c0 = (blockIdx.x & 63) << 6;
  int t  = threadIdx.x;
  int r  = t >> 2, dq = (t & 3) << 5;
  const float* src = of + ((size_t)(b*4096 + c0 + r))*128 + dq;
  float part = 0.f;
  #pragma unroll
  for (int j = 0; j < 32; j += 4){
    float4 v = *(const float4*)(src + j);
    part = fmaf(v.x, kvv[dq + j],     part);
    part = fmaf(v.y, kvv[dq + j + 1], part);
    part = fmaf(v.z, kvv[dq + j + 2], part);
    part = fmaf(v.w, kvv[dq + j + 3], part);
    tile[r*130 + dq + j]     = f2bf(v.x);
    tile[r*130 + dq + j + 1] = f2bf(v.y);
    tile[r*130 + dq + j + 2] = f2bf(v.z);
    tile[r*130 + dq + j + 3] = f2bf(v.w);
  }
  part += __shfl_xor(part, 1, 64);
  part += __shfl_xor(part, 2, 64);
  if ((t & 3) == 0) skp[b*4096 + c0 + r] = L2E * (part + cqck[1]);
  __syncthreads();
  int d = t >> 1, chh = (t & 1) << 5;
  unsigned short* dst = ofT + ((size_t)(b*128 + d))*4096 + c0 + chh;
  #pragma unroll
  for (int j = 0; j < 32; j += 8){
    u16x8 v;
    #pragma unroll
    for (int k = 0; k < 8; ++k) v[k] = tile[(chh + j + k)*130 + d];
    *(u16x8*)(dst + j) = v;
  }
}

// ---------------- main fused kernel (64-row tiles, contiguous loads) --------
// blk = ((b*16 + mt) << csl2) | cs. Block: rows [mt*64, +64), c-range
// [cs*(4096>>csl2), +4096>>csl2) in chunks of 128. Every mask/sk wave-load is
// per-instruction contiguous (lane l -> c=(l&31)*4, 2 adjacent rows/instr).
__global__ __launch_bounds__(256, 4) void attn_main(
    const float* __restrict__ mask, const float* __restrict__ sqp,
    const float* __restrict__ skp, const unsigned short* __restrict__ ofT,
    float* __restrict__ pacc, float* __restrict__ prs, int csl2)
{
  __shared__ unsigned short Pl[2][64*128];   // 2 x 16 KB, row stride 256 B
  const int blk = blockIdx.x;
  const int cs  = blk & ((1 << csl2) - 1);
  const int bmt = blk >> csl2;
  const int b   = bmt >> 4, mt = bmt & 15;
  const int m0  = mt << 6;
  const int c0  = cs << (12 - csl2);
  const int nch = 32 >> csl2;
  const int t = threadIdx.x, w = t >> 6, l = t & 63;
  const int l15 = l & 15, l4 = l >> 4, lh = l >> 5, l31 = l & 31;

  // P-phase: wave w handles rows [w*16, w*16+16); instr j -> rows w*16+2j+lh
  const int rbase = w*16 + lh;
  float sq8[8];
  #pragma unroll
  for (int j = 0; j < 8; ++j) sq8[j] = sqp[b*1024 + m0 + rbase + 2*j];

  const float* mbase  = mask + ((size_t)(b*1024 + m0 + rbase))*4096 + c0 + l31*4;
  const float* skbase = skp + b*4096 + c0 + l31*4;
  const unsigned short* bbase = ofT + ((size_t)(b*128 + w*32 + l15))*4096 + c0 + l4*8;

  f32x4 acc[4][2];
  #pragma unroll
  for (int mf = 0; mf < 4; ++mf){ acc[mf][0] = {0,0,0,0}; acc[mf][1] = {0,0,0,0}; }
  float rsum8[8] = {0,0,0,0,0,0,0,0};

  float4 pm[8], ps;
  #pragma unroll
  for (int j = 0; j < 8; ++j) pm[j] = *(const float4*)(mbase + (size_t)(2*j)*4096);
  ps = *(const float4*)(skbase);

  for (int ch = 0; ch < nch; ++ch){
    unsigned short* Pb = &Pl[ch & 1][0];
    float skx[4] = {ps.x, ps.y, ps.z, ps.w};
    #pragma unroll
    for (int j = 0; j < 8; ++j){
      float mm[4] = {pm[j].x, pm[j].y, pm[j].z, pm[j].w};
      const float sv = sq8[j];
      u16x4 hv;
      #pragma unroll
      for (int k = 0; k < 4; ++k){
        float s = sv + skx[k];            // log2-domain (pre-scaled by L2E)
        s = fmaxf(s, 0.01f*s);            // leaky (positively homogeneous)
        s *= mm[k];                       // mask: 0 -> exp2(0)=1
        float p = __builtin_amdgcn_exp2f(s);
        unsigned short h = f2bf(p);
        hv[k] = h;
        rsum8[j] += bf2f(h);              // denominator matches bf16 numerator
      }
      const int row = rbase + 2*j;
      *(u16x4*)((char*)Pb + row*256 + ((l31*8) ^ ((row & 7) << 4))) = hv;
    }
    __syncthreads();
    if (ch + 1 < nch){                     // prefetch next chunk under MFMA
      #pragma unroll
      for (int j = 0; j < 8; ++j)
        pm[j] = *(const float4*)(mbase + (size_t)(2*j)*4096 + (ch+1)*128);
      ps = *(const float4*)(skbase + (ch+1)*128);
    }
    const char* ab = (const char*)Pb + l15*256;
    const int xa = (l15 & 7) << 4;
    #pragma unroll
    for (int ks = 0; ks < 4; ++ks){
      short8 b0 = *(const short8*)(bbase + ch*128 + ks*32);
      short8 b1 = *(const short8*)(bbase + 16*4096 + ch*128 + ks*32);
      #pragma unroll
      for (int mf = 0; mf < 4; ++mf){
        short8 af = *(const short8*)(ab + mf*4096 + ((ks*64 + l4*16) ^ xa));
        acc[mf][0] = __builtin_amdgcn_mfma_f32_16x16x32_bf16(af, b0, acc[mf][0], 0, 0, 0);
        acc[mf][1] = __builtin_amdgcn_mfma_f32_16x16x32_bf16(af, b1, acc[mf][1], 0, 0, 0);
      }
    }
  }
  // per-row partial sums: lanes 0-31 / 32-63 each hold one row per j
  #pragma unroll
  for (int j = 0; j < 8; ++j){
    float s = rsum8[j];
    s += __shfl_xor(s, 1, 64);  s += __shfl_xor(s, 2, 64);
    s += __shfl_xor(s, 4, 64);  s += __shfl_xor(s, 8, 64);
    s += __shfl_xor(s, 16, 64);
    rsum8[j] = s;
  }
  if (l31 == 0){
    #pragma unroll
    for (int j = 0; j < 8; ++j) prs[blk*64 + rbase + 2*j] = rsum8[j];
  }
  float* pa = pacc + (size_t)blk * 8192;
  #pragma unroll
  for (int mf = 0; mf < 4; ++mf)
    #pragma unroll
    for (int n = 0; n < 2; ++n){
      const int col = w*32 + n*16 + l15;
      #pragma unroll
      for (int j = 0; j < 4; ++j)
        pa[(mf*16 + l4*4 + j)*128 + col] = acc[mf][n][j];
    }
}

// ---------------- reduce partials + normalize + GEMM2 ----------------
// grid 128: blk = b*16 + mt (64-row tile). Sums CS pacc slices, normalizes,
// then (64x128) @ W2(128x128) + c2 -> out.
__global__ __launch_bounds__(256) void reduce_gemm2(
    const float* __restrict__ pacc, const float* __restrict__ prs,
    const unsigned short* __restrict__ w2t, const float* __restrict__ c2,
    float* __restrict__ out, int csl2)
{
  __shared__ unsigned short A2[64*128];   // 16 KB, row stride 256 B
  __shared__ float rs[64];
  const int bmt = blockIdx.x;
  const int b = bmt >> 4, mt = bmt & 15;
  const int CS = 1 << csl2;
  const int t = threadIdx.x;
  const int base_blk = bmt << csl2;

  f32x4 a[8];
  #pragma unroll
  for (int i = 0; i < 8; ++i) a[i] = {0,0,0,0};
  for (int cs = 0; cs < CS; ++cs){
    const float* pb = pacc + (size_t)(base_blk + cs) * 8192;
    #pragma unroll
    for (int i = 0; i < 8; ++i){
      f32x4 v = *(const f32x4*)(pb + (i*256 + t)*4);
      a[i][0] += v[0]; a[i][1] += v[1]; a[i][2] += v[2]; a[i][3] += v[3];
    }
  }
  if (t < 64){
    float s = 0.f;
    for (int cs = 0; cs < CS; ++cs) s += prs[(base_blk + cs)*64 + t];
    rs[t] = s;
  }
  __syncthreads();
  #pragma unroll
  for (int i = 0; i < 8; ++i){
    const int flat = (i*256 + t)*4;
    const int row = flat >> 7, col = flat & 127;
    const float rinv = 1.f / rs[row];
    u16x4 hv;
    #pragma unroll
    for (int k = 0; k < 4; ++k) hv[k] = f2bf(a[i][k] * rinv);
    *(u16x4*)((char*)A2 + row*256 + ((col*2) ^ ((row & 7) << 4))) = hv;
  }
  __syncthreads();

  const int w = t >> 6, l = t & 63, l15 = l & 15, l4 = l >> 4;
  f32x4 o[4][2];
  #pragma unroll
  for (int mf = 0; mf < 4; ++mf){ o[mf][0] = {0,0,0,0}; o[mf][1] = {0,0,0,0}; }
  const unsigned short* wp0 = w2t + (size_t)(w*32 + l15)*128 + l4*8;
  const char* ab = (const char*)A2 + l15*256;
  const int xa = (l15 & 7) << 4;
  #pragma unroll
  for (int ks = 0; ks < 4; ++ks){
    short8 b0 = *(const short8*)(wp0 + ks*32);
    short8 b1 = *(const short8*)(wp0 + 16*128 + ks*32);
    #pragma unroll
    for (int mf = 0; mf < 4; ++mf){
      short8 af = *(const short8*)(ab + mf*4096 + ((ks*64 + l4*16) ^ xa));
      o[mf][0] = __builtin_amdgcn_mfma_f32_16x16x32_bf16(af, b0, o[mf][0], 0, 0, 0);
      o[mf][1] = __builtin_amdgcn_mfma_f32_16x16x32_bf16(af, b1, o[mf][1], 0, 0, 0);
    }
  }
  #pragma unroll
  for (int mf = 0; mf < 4; ++mf)
    #pragma unroll
    for (int n = 0; n < 2; ++n){
      const int col = w*32 + n*16 + l15;
      const float cc = c2[col];
      #pragma unroll
      for (int j = 0; j < 4; ++j){
        const int row = mf*16 + l4*4 + j;
        out[((size_t)(b*1024 + mt*64 + row))*128 + col] = o[mf][n][j] + cc;
      }
    }
}

extern "C" void kernel_launch(void* const* d_in, const int* in_sizes, int n_in,
                              void* d_out, int out_size, void* d_ws, size_t ws_size,
                              hipStream_t stream){
  const float* of   = (const float*)d_in[0];
  const float* mf   = (const float*)d_in[1];
  const float* mask = (const float*)d_in[2];
  const float* qw   = (const float*)d_in[3];
  const float* qb   = (const float*)d_in[4];
  const float* kvw  = (const float*)d_in[5];
  const float* kvb  = (const float*)d_in[6];
  const float* scw  = (const float*)d_in[7];
  const float* scb  = (const float*)d_in[8];
  const float* outw = (const float*)d_in[9];
  const float* outb = (const float*)d_in[10];
  float* out = (float*)d_out;

  char* ws = (char*)d_ws;
  unsigned short* ofT  = (unsigned short*)(ws);             // 8 MiB
  unsigned short* w2t  = (unsigned short*)(ws + 8388608);   // 32 KiB
  float* c2   = (float*)(ws + 8421376);
  float* sqp  = (float*)(ws + 8421888);
  float* skp  = (float*)(ws + 8454656);
  float* qv   = (float*)(ws + 8585728);
  float* kvv  = (float*)(ws + 8586240);
  float* cqck = (float*)(ws + 8586752);
  const size_t fixed_end = 8587008;

  // pick largest C-split that fits: blocks = 128 << csl2
  int csl2 = 3;
  for (; csl2 > 0; --csl2){
    size_t nblk = (size_t)128 << csl2;
    size_t need = fixed_end + nblk*64*4 + nblk*8192*4;
    if (need <= ws_size) break;
  }
  size_t nblk = (size_t)128 << csl2;
  float* prs  = (float*)(ws + fixed_end);
  float* pacc = (float*)(ws + fixed_end + nblk*64*4);

  prep_vecs<<<1, 128, 0, stream>>>(qw, qb, kvw, kvb, scw, scb, qv, kvv, cqck);
  prep_w2<<<65, 256, 0, stream>>>(kvw, kvb, outw, outb, w2t, c2);
  prep_sq<<<2048, 256, 0, stream>>>(mf, qv, cqck, sqp);
  prep_sk_tr<<<512, 256, 0, stream>>>(of, kvv, cqck, skp, ofT);
  attn_main<<<(int)nblk, 256, 0, stream>>>(mask, sqp, skp, ofT, pacc, prs, csl2);
  reduce_gemm2<<<128, 256, 0, stream>>>(pacc, prs, w2t, c2, out, csl2);
}